// Round 2
// 273.168 us; speedup vs baseline: 1.0581x; 1.0581x over previous
//
#include <hip/hip_runtime.h>
#include <stdint.h>

#define DEVFN __device__ __forceinline__

typedef short s16x8 __attribute__((ext_vector_type(8)));
typedef __bf16 bf16x8 __attribute__((ext_vector_type(8)));
typedef float fx4 __attribute__((ext_vector_type(4)));

// Problem constants (fixed by the reference)
constexpr int SEQ = 8192, DIM = 1280, HEADS = 16;
constexpr int NIMG = 32;
constexpr int NQKV = 3840;  // 3*DIM
constexpr int TS = 84;      // raw Q/K tile stride (168B rows: scatter = 2 lanes/bank, free)

DEVFN unsigned short f2bf(float f) {
  union { float f; unsigned u; } v; v.f = f;
  unsigned r = v.u + 0x7FFFu + ((v.u >> 16) & 1u);  // RNE
  return (unsigned short)(r >> 16);
}
DEVFN float bf2f(unsigned short u) {
  union { unsigned u; float f; } v; v.u = ((unsigned)u) << 16;
  return v.f;
}

DEVFN fx4 mfma16(s16x8 a, s16x8 b, fx4 c) {
  return __builtin_amdgcn_mfma_f32_16x16x32_bf16(
      __builtin_bit_cast(bf16x8, a), __builtin_bit_cast(bf16x8, b), c, 0, 0, 0);
}

DEVFN void gload_lds16(const void* g, void* l) {
  // global -> LDS direct, 16B per lane; LDS dest = wave-uniform base + lane*16
  __builtin_amdgcn_global_load_lds(
      (__attribute__((address_space(1))) void*)(uintptr_t)g,
      (__attribute__((address_space(3))) void*)l, 16, 0, 0);
}

// ---------------- f32 -> bf16 cast, 4 elems/thread ----------------
__global__ __launch_bounds__(256) void cast_bf16_kernel(const float* __restrict__ in,
                                                        unsigned short* __restrict__ out,
                                                        int n4) {
  int i = blockIdx.x * 256 + threadIdx.x;
  if (i >= n4) return;
  float4 v = ((const float4*)in)[i];
  ushort4 o;
  o.x = f2bf(v.x); o.y = f2bf(v.y); o.z = f2bf(v.z); o.w = f2bf(v.w);
  ((ushort4*)out)[i] = o;
}

// ---------------- transpose + cast: T[n][k] = W[k][n], bf16 out ----------------
__global__ __launch_bounds__(256) void transpose_cast_kernel(const float* __restrict__ W,
                                                             unsigned short* __restrict__ T,
                                                             int K, int N) {
  __shared__ float tile[32][33];
  const int tx = threadIdx.x & 31, ty = threadIdx.x >> 5;  // 32x8
  const int n0 = blockIdx.x * 32, k0 = blockIdx.y * 32;
#pragma unroll
  for (int i = 0; i < 4; i++) {
    int r = ty + i * 8;
    tile[r][tx] = W[(size_t)(k0 + r) * N + n0 + tx];
  }
  __syncthreads();
#pragma unroll
  for (int i = 0; i < 4; i++) {
    int r = ty + i * 8;
    T[(size_t)(n0 + r) * K + k0 + tx] = f2bf(tile[tx][r]);
  }
}

// ---------------- mega kernel: QKV GEMM + bias + RoPE + attention ----------------
// Block = (img n, head h), 512 threads = 8 waves (4x2). GEMM: 256x256x1280, BK=64,
// double-buffered LDS-DMA staging with raw-asm waitcnt+barrier (loads for k+1 in
// flight during compute k). Epilogue scatters acc+bias into stride-84 raw Q/K tiles
// and scatters V DIRECTLY TRANSPOSED into Vt[80][264] (kills the old 16-way-conflict
// V-transpose phase and barrier B5); then rope + QK^T + softmax + PV.
// LDS (153600 B): GEMM Abuf 2x32K @0, Bbuf 2x32K @65536 (dead after K-loop);
// X@0 (rawK84 -> Ks[256][104] -> P-scratch 8x16x264), Y@67584 (rawQ84),
// Vt@110592 (80x264, written in epilogue, read by PV).
__global__ __launch_bounds__(512, 2) void mega_attn(const unsigned short* __restrict__ hb,
                                                    const unsigned short* __restrict__ wqkvT,
                                                    const float* __restrict__ b_qkv,
                                                    const float* __restrict__ cosb,
                                                    const float* __restrict__ sinb,
                                                    unsigned short* __restrict__ Ob) {
  __shared__ __attribute__((aligned(16))) char smem[153600];
  unsigned short* X = (unsigned short*)smem;
  unsigned short* Y = (unsigned short*)(smem + 67584);
  unsigned short* Vt = (unsigned short*)(smem + 110592);  // [80][264]
  char* Abuf = smem;          // 2 x 32768
  char* Bbuf = smem + 65536;  // 2 x 32768

  const int t = threadIdx.x;
  const int lane = t & 63, w = t >> 6;
  const int lrow = lane & 15, lq = lane >> 4;
  const int l7 = lrow & 7;
  const int n = blockIdx.x, h = blockIdx.y;
  const int s0 = n * 256;
  const int wm = w >> 1, wn = w & 1;

  // staging geometry: per matrix 2048 16B-chunks/iter; thread covers slots i*512+t.
  // slot s -> row r = s>>3 (= i*64 + (t>>3)); stored chunk t&7 holds global chunk
  // (t&7)^(r&7) (XOR-8 swizzle -> conflict-free ds_read_b128).
  const int tr3 = t >> 3;
  const int cchunk = ((t & 7) ^ (tr3 & 7)) * 8;
  const unsigned short* pA = hb + (size_t)(s0 + tr3) * 1280 + cchunk;
  const unsigned short* pB[4];
#pragma unroll
  for (int i = 0; i < 4; i++) {
    const int r = i * 64 + tr3;
    const int rr = r < 240 ? r : 239;  // pad rows clamp (cols 240..255 never used)
    const int sgm = (rr >= 160) ? 2 : (rr >= 80 ? 1 : 0);
    pB[i] = wqkvT + (size_t)(sgm * DIM + h * 80 + (rr - sgm * 80)) * 1280 + cchunk;
  }

  int offA[4][2], offB[8][2];
#pragma unroll
  for (int i = 0; i < 4; i++) {
    const int ra = wm * 64 + i * 16 + lrow;
    offA[i][0] = ra * 128 + (lq ^ l7) * 16;
    offA[i][1] = ra * 128 + ((lq + 4) ^ l7) * 16;
  }
#pragma unroll
  for (int j = 0; j < 8; j++) {
    const int rb = wn * 128 + j * 16 + lrow;
    offB[j][0] = rb * 128 + (lq ^ l7) * 16;
    offB[j][1] = rb * 128 + ((lq + 4) ^ l7) * 16;
  }

  fx4 acc[4][8] = {};

  // prologue: stage k=0 into buf0
  {
    char* da = Abuf + w * 1024;
    char* db = Bbuf + w * 1024;
#pragma unroll
    for (int i = 0; i < 4; i++) {
      gload_lds16(pA + (size_t)i * 64 * 1280, da + i * 8192);
      gload_lds16(pB[i], db + i * 8192);
    }
  }

  for (int k = 0; k < 20; k++) {
    // drain own buf[k] loads, then barrier => everyone's buf[k] complete and
    // everyone finished reading buf[k&1] from iter k-2. Raw asm: no full
    // __syncthreads drain of the loads we issue below.
    asm volatile("s_waitcnt vmcnt(0)\n\ts_barrier" ::: "memory");
    if (k < 19) {  // issue buf[k+1] now; flies during compute(k)
      const int kof = (k + 1) * 64;
      char* da = Abuf + ((k + 1) & 1) * 32768 + w * 1024;
      char* db = Bbuf + ((k + 1) & 1) * 32768 + w * 1024;
#pragma unroll
      for (int i = 0; i < 4; i++) {
        gload_lds16(pA + (size_t)i * 64 * 1280 + kof, da + i * 8192);
        gload_lds16(pB[i] + kof, db + i * 8192);
      }
    }
    const char* As = Abuf + (k & 1) * 32768;
    const char* Bs = Bbuf + (k & 1) * 32768;
#pragma unroll
    for (int kq = 0; kq < 2; kq++) {
      s16x8 a[4], b[8];
#pragma unroll
      for (int i = 0; i < 4; i++) a[i] = *(const s16x8*)(As + offA[i][kq]);
#pragma unroll
      for (int j = 0; j < 8; j++) b[j] = *(const s16x8*)(Bs + offB[j][kq]);
#pragma unroll
      for (int i = 0; i < 4; i++)
#pragma unroll
        for (int j = 0; j < 8; j++)
          acc[i][j] = mfma16(a[i], b[j], acc[i][j]);
    }
  }
  __syncthreads();  // all fragment reads done before staging regions become Q/K/Vt

  // ---- epilogue scatter: acc + bias -> raw Q (Y), K (X) @stride 84;
  //      V goes DIRECTLY TRANSPOSED into Vt[d][key] (d=col-160, key=row).
  //      Vt store banks: (4*lrow + 2*lq) mod 32 -> <=4-way on 2B stores, cheap.
#pragma unroll
  for (int j = 0; j < 8; j++) {
    const int col = wn * 128 + j * 16 + lrow;
    if (col < 240) {
      const int sgm = (col >= 160) ? 2 : (col >= 80 ? 1 : 0);
      const int d = col - sgm * 80;
      const float bv = b_qkv[sgm * DIM + h * 80 + d];
      if (sgm == 2) {
#pragma unroll
        for (int i = 0; i < 4; i++) {
          const int rowb = wm * 64 + i * 16 + lq * 4;
#pragma unroll
          for (int r = 0; r < 4; r++)
            Vt[(size_t)d * 264 + rowb + r] = f2bf(acc[i][j][r] + bv);
        }
      } else {
        unsigned short* dst = sgm ? X : Y;
#pragma unroll
        for (int i = 0; i < 4; i++) {
          const int row = wm * 64 + i * 16 + lq * 4;
#pragma unroll
          for (int r = 0; r < 4; r++)
            dst[(row + r) * TS + d] = f2bf(acc[i][j][r] + bv);
        }
      }
    }
  }
  __syncthreads();  // B1: raw Q/K + Vt complete

  // ---- K rope -> regs; Q rope -> A-fragments (wave w owns q-rows w*32..w*32+31) ----
  unsigned short kout[5][8];
  int kro[5], kco[5];
#pragma unroll
  for (int i = 0; i < 5; i++) {
    const int idx = t + i * 512;
    const unsigned r = (unsigned)idx / 10u, c = (unsigned)idx % 10u;
    kro[i] = r; kco[i] = c;
    s16x8 xv = *(const s16x8*)&X[r * TS + c * 8];
    const unsigned cp = (c < 5) ? c + 5 : c - 5;  // partner chunk (+-40 elems)
    s16x8 pv = *(const s16x8*)&X[r * TS + cp * 8];
    const float sgn = (c < 5) ? -1.f : 1.f;
    const float* cf = cosb + (size_t)(s0 + r) * 80 + c * 8;
    const float* sf = sinb + (size_t)(s0 + r) * 80 + c * 8;
#pragma unroll
    for (int j = 0; j < 8; j++)
      kout[i][j] = f2bf(bf2f((unsigned short)xv[j]) * cf[j] +
                        sgn * bf2f((unsigned short)pv[j]) * sf[j]);
  }

  s16x8 aq[2][3];
#pragma unroll
  for (int rt = 0; rt < 2; rt++) {
#pragma unroll
    for (int c = 0; c < 3; c++) {
      const int row = w * 32 + rt * 16 + lrow;
      const int d0 = c * 32 + lq * 8;
      s16x8 fr = {};
      if (d0 < 80) {
        s16x8 xv = *(const s16x8*)&Y[row * TS + d0];
        const int dp = (d0 < 40) ? d0 + 40 : d0 - 40;
        s16x8 pv = *(const s16x8*)&Y[row * TS + dp];
        const float sgn = (d0 < 40) ? -1.f : 1.f;
        const float* cf = cosb + (size_t)(s0 + row) * 80 + d0;
        const float* sf = sinb + (size_t)(s0 + row) * 80 + d0;
#pragma unroll
        for (int j = 0; j < 8; j++)
          fr[j] = (short)f2bf(bf2f((unsigned short)xv[j]) * cf[j] +
                              sgn * bf2f((unsigned short)pv[j]) * sf[j]);
      }
      aq[rt][c] = fr;
    }
  }
  __syncthreads();  // B2: rawK/rawQ reads done

  // ---- write rope'd K at stride 104 (2-way bank aliasing = free) + zero pad ----
#pragma unroll
  for (int i = 0; i < 5; i++)
    *(int4*)&X[kro[i] * 104 + kco[i] * 8] = *(const int4*)kout[i];
  {
    const int r = t >> 1, wh = t & 1;
    const int4 z = {0, 0, 0, 0};
    *(int4*)&X[r * 104 + 80 + wh * 8] = z;
  }
  __syncthreads();  // B3

  // ---- QK^T: 2 row-tiles x 16 col-tiles, K = 96 ----
  fx4 acc2[2][16] = {};
#pragma unroll
  for (int c = 0; c < 3; c++) {
#pragma unroll
    for (int ct = 0; ct < 16; ct++) {
      s16x8 b = *(const s16x8*)&X[(ct * 16 + lrow) * 104 + c * 32 + lq * 8];
      acc2[0][ct] = mfma16(aq[0][c], b, acc2[0][ct]);
      acc2[1][ct] = mfma16(aq[1][c], b, acc2[1][ct]);
    }
  }

  // ---- softmax (rows wave-local: row = rt*16 + lq*4 + r) ----
  const float kscale = 0.11180339887498949f * 1.4426950408889634f;  // 80^-0.5 * log2e
  float inv[2][4];
#pragma unroll
  for (int rt = 0; rt < 2; rt++) {
    float mx[4] = {-1e30f, -1e30f, -1e30f, -1e30f};
#pragma unroll
    for (int ct = 0; ct < 16; ct++)
#pragma unroll
      for (int r = 0; r < 4; r++) mx[r] = fmaxf(mx[r], acc2[rt][ct][r]);
#pragma unroll
    for (int r = 0; r < 4; r++) {
      mx[r] = fmaxf(mx[r], __shfl_xor(mx[r], 1));
      mx[r] = fmaxf(mx[r], __shfl_xor(mx[r], 2));
      mx[r] = fmaxf(mx[r], __shfl_xor(mx[r], 4));
      mx[r] = fmaxf(mx[r], __shfl_xor(mx[r], 8));
    }
    float sm[4] = {0.f, 0.f, 0.f, 0.f};
#pragma unroll
    for (int ct = 0; ct < 16; ct++)
#pragma unroll
      for (int r = 0; r < 4; r++) {
        float e = exp2f((acc2[rt][ct][r] - mx[r]) * kscale);
        acc2[rt][ct][r] = e;
        sm[r] += e;
      }
#pragma unroll
    for (int r = 0; r < 4; r++) {
      sm[r] += __shfl_xor(sm[r], 1);
      sm[r] += __shfl_xor(sm[r], 2);
      sm[r] += __shfl_xor(sm[r], 4);
      sm[r] += __shfl_xor(sm[r], 8);
      inv[rt][r] = 1.f / sm[r];
    }
  }
  __syncthreads();  // B4: Ks dead; X becomes per-wave P-scratch

  // ---- P (rt=0) to per-wave scratch (wave-private: only lgkmcnt ordering needed,
  //      compiler inserts it; Vt has been complete since B1 -> no barrier here) ----
  unsigned short* Pw = X + w * 4224;  // 16 rows x 264 elems
#pragma unroll
  for (int ct = 0; ct < 16; ct++)
#pragma unroll
    for (int r = 0; r < 4; r++)
      Pw[(lq * 4 + r) * 264 + ct * 16 + lrow] = f2bf(acc2[0][ct][r] * inv[0][r]);

  // ---- PV + output, two 16-row sweeps ----
#pragma unroll
  for (int rt = 0; rt < 2; rt++) {
    if (rt == 1) {
#pragma unroll
      for (int ct = 0; ct < 16; ct++)
#pragma unroll
        for (int r = 0; r < 4; r++)
          Pw[(lq * 4 + r) * 264 + ct * 16 + lrow] = f2bf(acc2[1][ct][r] * inv[1][r]);
    }
    fx4 accO[5] = {};
#pragma unroll
    for (int kc = 0; kc < 8; kc++) {
      s16x8 a = *(const s16x8*)&Pw[lrow * 264 + kc * 32 + lq * 8];
#pragma unroll
      for (int tt = 0; tt < 5; tt++) {
        s16x8 b = *(const s16x8*)&Vt[(tt * 16 + lrow) * 264 + kc * 32 + lq * 8];
        accO[tt] = mfma16(a, b, accO[tt]);
      }
    }
    const int srow = s0 + w * 32 + rt * 16 + lq * 4;
#pragma unroll
    for (int tt = 0; tt < 5; tt++) {
      const int col = h * 80 + tt * 16 + lrow;
#pragma unroll
      for (int r = 0; r < 4; r++)
        Ob[(size_t)(srow + r) * DIM + col] = f2bf(accO[tt][r]);
    }
  }
}

// ---------------- proj GEMM: 128x128, BK=64, LDS-DMA double-buffered ----------------
// Same staging structure as mega's GEMM (global_load_lds width-16 + XOR-8 swizzle,
// raw vmcnt(0)+s_barrier per K-step, loads for k+1 in flight during compute k).
// LDS 64 KB -> 2 blocks/CU. Replaces the reg-prefetch version (m151: gload_lds
// staging is ~+35% on this exact 128^2 tile).
__global__ __launch_bounds__(256, 2) void gemm_proj(const unsigned short* __restrict__ A,
                                                    const unsigned short* __restrict__ Bt,
                                                    const float* __restrict__ bias,
                                                    float* __restrict__ C) {
  __shared__ __attribute__((aligned(16))) char smem[65536];
  char* Abuf = smem;          // 2 x 16384
  char* Bbuf = smem + 32768;  // 2 x 16384
  const int t = threadIdx.x;
  const int lane = t & 63, w = t >> 6;
  const int lrow = lane & 15, lq = lane >> 4;
  const int l7 = lrow & 7;
  const int wm = w >> 1, wn = w & 1;  // 2x2 wave grid, 64x64 tiles
  const int m0 = blockIdx.x * 128, n0 = blockIdx.y * 128;

  // staging: per matrix 1024 16B-chunks/iter; thread covers slots i*256+t (i=0..3).
  // slot s -> row r = s>>3 = i*32 + (t>>3); stored chunk t&7 = global (t&7)^(r&7).
  const int tr3 = t >> 3;
  const int cchunk = ((t & 7) ^ (tr3 & 7)) * 8;
  const unsigned short* pA = A + (size_t)(m0 + tr3) * 1280 + cchunk;
  const unsigned short* pBt = Bt + (size_t)(n0 + tr3) * 1280 + cchunk;

  int offA[4][2], offB[4][2];
#pragma unroll
  for (int i = 0; i < 4; i++) {
    const int ra = wm * 64 + i * 16 + lrow;
    const int rb = wn * 64 + i * 16 + lrow;
    offA[i][0] = ra * 128 + (lq ^ l7) * 16;
    offA[i][1] = ra * 128 + ((lq + 4) ^ l7) * 16;
    offB[i][0] = rb * 128 + (lq ^ l7) * 16;
    offB[i][1] = rb * 128 + ((lq + 4) ^ l7) * 16;
  }

  fx4 acc[4][4] = {};

  // prologue: stage k=0 into buf0
  {
    char* da = Abuf + w * 1024;
    char* db = Bbuf + w * 1024;
#pragma unroll
    for (int i = 0; i < 4; i++) {
      gload_lds16(pA + (size_t)i * 32 * 1280, da + i * 4096);
      gload_lds16(pBt + (size_t)i * 32 * 1280, db + i * 4096);
    }
  }

  for (int k = 0; k < 20; k++) {
    asm volatile("s_waitcnt vmcnt(0)\n\ts_barrier" ::: "memory");
    if (k < 19) {  // issue buf[k+1]; flies during compute(k)
      const int kof = (k + 1) * 64;
      char* da = Abuf + ((k + 1) & 1) * 16384 + w * 1024;
      char* db = Bbuf + ((k + 1) & 1) * 16384 + w * 1024;
#pragma unroll
      for (int i = 0; i < 4; i++) {
        gload_lds16(pA + (size_t)i * 32 * 1280 + kof, da + i * 4096);
        gload_lds16(pBt + (size_t)i * 32 * 1280 + kof, db + i * 4096);
      }
    }
    const char* As = Abuf + (k & 1) * 16384;
    const char* Bs = Bbuf + (k & 1) * 16384;
#pragma unroll
    for (int kq = 0; kq < 2; kq++) {
      s16x8 a[4], b[4];
#pragma unroll
      for (int i = 0; i < 4; i++) a[i] = *(const s16x8*)(As + offA[i][kq]);
#pragma unroll
      for (int j = 0; j < 4; j++) b[j] = *(const s16x8*)(Bs + offB[j][kq]);
#pragma unroll
      for (int i = 0; i < 4; i++)
#pragma unroll
        for (int j = 0; j < 4; j++)
          acc[i][j] = mfma16(a[i], b[j], acc[i][j]);
    }
  }

#pragma unroll
  for (int i = 0; i < 4; i++) {
    const int row_base = m0 + wm * 64 + i * 16 + lq * 4;
#pragma unroll
    for (int j = 0; j < 4; j++) {
      const int col = n0 + wn * 64 + j * 16 + lrow;
      const float bv = bias[col];
#pragma unroll
      for (int r = 0; r < 4; r++)
        C[(size_t)(row_base + r) * DIM + col] = acc[i][j][r] + bv;
    }
  }
}

// ---------------- launch ----------------
extern "C" void kernel_launch(void* const* d_in, const int* in_sizes, int n_in,
                              void* d_out, int out_size, void* d_ws, size_t ws_size,
                              hipStream_t stream) {
  const float* hidden = (const float*)d_in[0];
  // d_in[1] = cu_seqlens: fixed layout (32 chunks of 256), unused
  const float* cosb = (const float*)d_in[2];
  const float* sinb = (const float*)d_in[3];
  const float* w_qkv = (const float*)d_in[4];
  const float* b_qkv = (const float*)d_in[5];
  const float* w_proj = (const float*)d_in[6];
  const float* b_proj = (const float*)d_in[7];
  float* out = (float*)d_out;

  // workspace layout (bytes)
  char* ws = (char*)d_ws;
  constexpr size_t HB_B = (size_t)SEQ * DIM * 2;    // 20,971,520 hidden bf16
  constexpr size_t WQT_B = (size_t)NQKV * DIM * 2;  //  9,830,400 w_qkv^T bf16
  constexpr size_t WPT_B = (size_t)DIM * DIM * 2;   //  3,276,800 w_proj^T bf16
  constexpr size_t OB_B = (size_t)SEQ * DIM * 2;    // 20,971,520 attn out bf16
  size_t off = 0;
  unsigned short* hb = (unsigned short*)(ws + off);     off += HB_B;
  unsigned short* wqkvT = (unsigned short*)(ws + off);  off += WQT_B;
  unsigned short* wprojT = (unsigned short*)(ws + off); off += WPT_B;
  unsigned short* Ob = (unsigned short*)(ws + off);     off += OB_B;
  if (ws_size < off) return;

  // 1. cast hidden to bf16
  cast_bf16_kernel<<<dim3((SEQ * DIM / 4 + 255) / 256), dim3(256), 0, stream>>>(
      hidden, hb, SEQ * DIM / 4);
  // 2. transpose-cast weights
  transpose_cast_kernel<<<dim3(NQKV / 32, DIM / 32), dim3(256), 0, stream>>>(
      w_qkv, wqkvT, DIM, NQKV);
  transpose_cast_kernel<<<dim3(DIM / 32, DIM / 32), dim3(256), 0, stream>>>(
      w_proj, wprojT, DIM, DIM);
  // 3. mega: QKV GEMM + RoPE + attention -> Ob
  mega_attn<<<dim3(NIMG, HEADS), dim3(512), 0, stream>>>(hb, wqkvT, b_qkv, cosb, sinb, Ob);
  // 4. proj GEMM (+bias) -> d_out (f32)
  gemm_proj<<<dim3(SEQ / 128, DIM / 128), dim3(256), 0, stream>>>(
      Ob, wprojT, b_proj, out);
}